// Round 14
// baseline (326.494 us; speedup 1.0000x reference)
//
#include <hip/hip_runtime.h>
#include <math.h>

#define Tt 250
#define TnN 243
#define Nn 256
#define EPS_ 1e-5f
#define LOG2E 1.44269504f

typedef unsigned short u16;
typedef __bf16 bf16x8 __attribute__((ext_vector_type(8)));
typedef float f32x4 __attribute__((ext_vector_type(4)));

__device__ __forceinline__ u16 f2bf(float f) {
    unsigned u = __builtin_bit_cast(unsigned, f);
    u += 0x7FFFu + ((u >> 16) & 1u);
    return (u16)(u >> 16);
}
__device__ __forceinline__ float bf2f(u16 s) {
    unsigned u = ((unsigned)s) << 16;
    return __builtin_bit_cast(float, u);
}
__device__ __forceinline__ float hw_exp2(float x) {
    return __builtin_amdgcn_exp2f(x);
}

__device__ __forceinline__ void async_load16(const void* g, void* l) {
    __builtin_amdgcn_global_load_lds(
        (const __attribute__((address_space(1))) unsigned int*)g,
        (__attribute__((address_space(3))) unsigned int*)l, 16, 0, 0);
}

// DMA one 15,552 B plane (243x32 u16) global->LDS, 4 waves cooperate
__device__ __forceinline__ void dma_plane(const u16* gsrc, u16* ldst, int w, int lane) {
    const char* g = (const char*)gsrc;
    char* l = (char*)ldst;
    for (int off = w * 1024; off < 15552; off += 4096) {
        int rem = 15552 - off;
        int lim = rem < 1024 ? rem : 1024;
        if (lane * 16 < lim) async_load16(g + off + lane * 16, l + off);
    }
}

// ---------------- stats ----------------
__global__ void k_stats(const float* __restrict__ x, float* __restrict__ stats) {
    int b = blockIdx.y;
    const float* xb = x + (size_t)b * 64 * 128 * Tt;
    const int n = 64 * 128 * Tt;
    float s = 0.f, s2 = 0.f;
    for (int i = blockIdx.x * blockDim.x + threadIdx.x; i < n; i += gridDim.x * blockDim.x) {
        float v = xb[i];
        s += v; s2 += v * v;
    }
    for (int off = 32; off; off >>= 1) {
        s  += __shfl_down(s, off);
        s2 += __shfl_down(s2, off);
    }
    __shared__ float ls[8], ls2[8];
    int lane = threadIdx.x & 63, w = threadIdx.x >> 6;
    if (lane == 0) { ls[w] = s; ls2[w] = s2; }
    __syncthreads();
    if (threadIdx.x == 0) {
        float a = 0.f, a2 = 0.f;
        int nw = blockDim.x >> 6;
        for (int i = 0; i < nw; i++) { a += ls[i]; a2 += ls2[i]; }
        atomicAdd(&stats[b * 2 + 0], a);
        atomicAdd(&stats[b * 2 + 1], a2);
    }
}

// ---------------- normalize ----------------
__global__ void k_norm(const float* __restrict__ x, const float* __restrict__ stats,
                       const float* __restrict__ gamma, const float* __restrict__ beta,
                       float* __restrict__ xu) {
    int idx = blockIdx.x * blockDim.x + threadIdx.x;
    const int total = Nn * 64 * Tt;
    if (idx >= total) return;
    int t = idx % Tt;
    int c = (idx / Tt) & 63;
    int n = idx / (Tt * 64);
    int b = n >> 7, f = n & 127;
    const float inv = 1.0f / (float)(64 * 128 * Tt);
    float mean = stats[b * 2 + 0] * inv;
    float var  = stats[b * 2 + 1] * inv - mean * mean;
    float rstd = rsqrtf(var + EPS_);
    float v = x[(((size_t)(b * 64 + c)) * 128 + f) * Tt + t];
    xu[((size_t)(n * 64 + c) << 8) + t] = (v - mean) * rstd * gamma[c] + beta[c];
}

// ---------------- pack weights ----------------
__global__ void k_packw(const float* __restrict__ W0, const float* __restrict__ Wr,
                        const float* __restrict__ wct,
                        u16* __restrict__ W0t, u16* __restrict__ Wrt, u16* __restrict__ Wcto) {
    int idx = blockIdx.x * blockDim.x + threadIdx.x;
    if (idx < 131072) {
        int j = idx >> 9, p = idx & 511;
        W0t[idx] = f2bf(W0[(size_t)(j >> 7) * 65536 + p * 128 + (j & 127)]);
    } else if (idx < 180224) {
        int r = idx - 131072;
        int i = r & 63, j = (r >> 6) & 255, lidx = r >> 14;
        Wrt[r] = f2bf(Wr[(size_t)(lidx * 2 + (j >> 7)) * 8192 + i * 128 + (j & 127)]);
    } else if (idx < 212992) {
        int r = idx - 180224;
        int o = r >> 9; int k = r & 511; int kk = k >> 6, ci = k & 63;
        Wcto[r] = f2bf(wct[(size_t)ci * 512 + o * 8 + kk]);
    }
}

// ---------------- im2col ----------------
__global__ __launch_bounds__(256) void k_im2col(const float* __restrict__ xu, u16* __restrict__ A) {
    __shared__ u16 lx[8][64][40];
    int t0 = blockIdx.x * 32;
    int n0 = blockIdx.y * 8;
    int tid = threadIdx.x;
    #pragma unroll
    for (int it = 0; it < 20; ++it) {
        int task = tid + it * 256;
        int v = task % 10;
        int c = (task / 10) & 63;
        int nn = task / 640;
        float4 f4 = *(const float4*)&xu[((size_t)((n0 + nn) * 64 + c) << 8) + t0 + v * 4];
        lx[nn][c][v * 4 + 0] = f2bf(f4.x);
        lx[nn][c][v * 4 + 1] = f2bf(f4.y);
        lx[nn][c][v * 4 + 2] = f2bf(f4.z);
        lx[nn][c][v * 4 + 3] = f2bf(f4.w);
    }
    __syncthreads();
    for (int it = 0; it < 64; ++it) {
        int task = it * 256 + tid;
        int c = task & 63, nn = (task >> 6) & 7, tt = task >> 9;
        int t = t0 + tt;
        if (t >= TnN) break;
        u16 tmp[8];
        #pragma unroll
        for (int j = 0; j < 8; ++j) tmp[j] = lx[nn][c][tt + j];
        uint4 o;
        o.x = (unsigned)tmp[0] | ((unsigned)tmp[1] << 16);
        o.y = (unsigned)tmp[2] | ((unsigned)tmp[3] << 16);
        o.z = (unsigned)tmp[4] | ((unsigned)tmp[5] << 16);
        o.w = (unsigned)tmp[6] | ((unsigned)tmp[7] << 16);
        *(uint4*)&A[((size_t)t * 256 + n0 + nn) * 512 + c * 8] = o;
    }
}

// ---------------- MFMA GEMM layer 0 -> U2 gate planes [n][d][g][243][32] ----------------
__global__ __launch_bounds__(256) void k_gemm0m(const u16* __restrict__ A,
                                                const u16* __restrict__ B,
                                                u16* __restrict__ U2) {
    __shared__ u16 sh[16384];
    u16* As = sh;
    u16* Bs = sh + 5120;
    const int tid = threadIdx.x;
    const size_t m0 = (size_t)blockIdx.x * 128;
    const int t = blockIdx.x >> 1;
    const int n0 = (blockIdx.x & 1) * 128;
    const int j0 = blockIdx.y * 128;
    const int d = blockIdx.y;
    const int lane = tid & 63, w = tid >> 6;
    const int wr = w >> 1, wc = w & 1;
    const int ml = lane & 15, q = lane >> 4;
    f32x4 acc[4][4] = {};
    for (int kc = 0; kc < 16; ++kc) {
        int c0 = kc * 32;
        #pragma unroll
        for (int i = 0; i < 2; ++i) {
            int task = tid + i * 256;
            int row = task >> 2, grp = task & 3;
            *(uint4*)&As[row * 40 + grp * 8] = *(const uint4*)&A[(m0 + row) * 512 + c0 + grp * 8];
            *(uint4*)&Bs[row * 40 + grp * 8] = *(const uint4*)&B[(size_t)(j0 + row) * 512 + c0 + grp * 8];
        }
        __syncthreads();
        bf16x8 af[4], bfv[4];
        #pragma unroll
        for (int mt = 0; mt < 4; ++mt) af[mt] = *(const bf16x8*)&As[(wr * 64 + mt * 16 + ml) * 40 + q * 8];
        #pragma unroll
        for (int nt = 0; nt < 4; ++nt) bfv[nt] = *(const bf16x8*)&Bs[(wc * 64 + nt * 16 + ml) * 40 + q * 8];
        #pragma unroll
        for (int mt = 0; mt < 4; ++mt)
            #pragma unroll
            for (int nt = 0; nt < 4; ++nt)
                acc[mt][nt] = __builtin_amdgcn_mfma_f32_16x16x32_bf16(af[mt], bfv[nt], acc[mt][nt], 0, 0, 0);
        __syncthreads();
    }
    u16* Cw = sh + w * 4096;
    #pragma unroll
    for (int mt = 0; mt < 4; ++mt)
        #pragma unroll
        for (int nt = 0; nt < 4; ++nt)
            #pragma unroll
            for (int r = 0; r < 4; ++r)
                Cw[(mt * 16 + q * 4 + r) * 64 + nt * 16 + ml] = f2bf(acc[mt][nt][r]);
    __syncthreads();
    #pragma unroll
    for (int it = 0; it < 8; ++it) {
        int task = it * 64 + lane;
        int grp = task & 7, row = task >> 3;
        int n = n0 + wr * 64 + row;
        int jj = wc * 64 + grp * 8;
        int g2 = jj >> 5;
        int h0 = jj & 31;
        *(uint4*)&U2[(((size_t)(n * 2 + d) * 4 + g2) * 7776) + t * 32 + h0] =
            *(const uint4*)&Cw[row * 64 + grp * 8];
    }
}

// ---------------- mega tail ----------------
// LDS map (u16 offsets): Hs 0..19007 (264x72), ZT 19008 (64x248), FT 34880 (64x248),
//                        Rs 50752 (2x243x32), Xs 66304 (2x243x32). Total 81856 u16 = 163,712 B
#define HS0 0
#define ZT0 19008
#define FT0 34880
#define RS0 50752
#define XS0 66304
#define SH_U16 81856
__global__ __launch_bounds__(256) void k_tail(const u16* __restrict__ U2,
                                              const u16* __restrict__ Wrt,
                                              const u16* __restrict__ Wc,
                                              const float* __restrict__ v,
                                              const float* __restrict__ bbias,
                                              const float* __restrict__ bct,
                                              const float* __restrict__ x,
                                              float* __restrict__ out) {
    __shared__ u16 sh[SH_U16];
    u16* Hs = sh + HS0;
    u16* ZT = sh + ZT0;
    u16* FT = sh + FT0;
    u16* Rs = sh + RS0;
    u16* Xs = sh + XS0;
    const int tid = threadIdx.x;
    const int n = blockIdx.x;
    const int lane = tid & 63, w = tid >> 6;
    const int ml = lane & 15, q = lane >> 4;
    const u16* U2n = U2 + (size_t)n * 62208;   // FIX: per-n stride is 2 d x 4 g x 7776 = 62208

    for (int lay = 0; lay < 4; ++lay) {
        if (lay == 0) {
            // round A: z planes -> Hs staging; r,x planes -> finals
            for (int d2 = 0; d2 < 2; ++d2) {
                dma_plane(U2n + (size_t)(d2 * 4 + 0) * 7776, Hs + d2 * 7776, w, lane);
                dma_plane(U2n + (size_t)(d2 * 4 + 2) * 7776, Rs + d2 * 7776, w, lane);
                dma_plane(U2n + (size_t)(d2 * 4 + 3) * 7776, Xs + d2 * 7776, w, lane);
            }
            __syncthreads();
            {   // transpose z: Hs[d][t][h] -> ZT[(d*32+h)][t]
                int cd = tid & 63, dd = cd >> 5, hh = cd & 31, tq = tid >> 6;
                int tb = tq * 61, te = tb + 61 < TnN ? tb + 61 : TnN;
                for (int t = tb; t < te; ++t)
                    ZT[cd * 248 + t] = Hs[dd * 7776 + t * 32 + hh];
            }
            __syncthreads();
            for (int d2 = 0; d2 < 2; ++d2)
                dma_plane(U2n + (size_t)(d2 * 4 + 1) * 7776, Hs + d2 * 7776, w, lane);
            __syncthreads();
            {   // transpose f
                int cd = tid & 63, dd = cd >> 5, hh = cd & 31, tq = tid >> 6;
                int tb = tq * 61, te = tb + 61 < TnN ? tb + 61 : TnN;
                for (int t = tb; t < te; ++t)
                    FT[cd * 248 + t] = Hs[dd * 7776 + t * 32 + hh];
            }
        } else {
            // B staging in (dead) ZT region
            u16* Bst = sh + ZT0;     // 256 x 72
            const u16* Wl = Wrt + (size_t)(lay - 1) * 16384;
            #pragma unroll
            for (int it = 0; it < 8; ++it) {
                int task = it * 256 + tid;
                int j = task >> 3, grp = task & 7;
                *(uint4*)&Bst[j * 72 + grp * 8] = *(const uint4*)&Wl[j * 64 + grp * 8];
            }
            __syncthreads();
            f32x4 acc[4][16];
            #pragma unroll
            for (int mt = 0; mt < 4; ++mt)
                #pragma unroll
                for (int nt = 0; nt < 16; ++nt)
                    acc[mt][nt] = (f32x4){0.f, 0.f, 0.f, 0.f};
            #pragma unroll
            for (int c2 = 0; c2 < 2; ++c2) {
                int c0 = c2 * 32;
                bf16x8 af[4];
                #pragma unroll
                for (int mt = 0; mt < 4; ++mt)
                    af[mt] = *(const bf16x8*)&Hs[(w * 64 + mt * 16 + ml + 7) * 72 + c0 + q * 8];
                #pragma unroll
                for (int nt = 0; nt < 16; ++nt) {
                    bf16x8 bfr = *(const bf16x8*)&Bst[(nt * 16 + ml) * 72 + c0 + q * 8];
                    #pragma unroll
                    for (int mt = 0; mt < 4; ++mt)
                        acc[mt][nt] = __builtin_amdgcn_mfma_f32_16x16x32_bf16(af[mt], bfr, acc[mt][nt], 0, 0, 0);
                }
            }
            __syncthreads();   // all B reads done -> ZT/FT writable
            #pragma unroll
            for (int mt = 0; mt < 4; ++mt)
                #pragma unroll
                for (int r = 0; r < 4; ++r) {
                    int t = w * 64 + mt * 16 + q * 4 + r;
                    if (t < TnN) {
                        #pragma unroll
                        for (int nt = 0; nt < 16; ++nt) {
                            int d2 = nt >> 3, g2 = (nt >> 1) & 3, hh = (nt & 1) * 16 + ml;
                            u16 val = f2bf(acc[mt][nt][r]);
                            if (g2 == 0)      ZT[(d2 * 32 + hh) * 248 + t] = val;
                            else if (g2 == 1) FT[(d2 * 32 + hh) * 248 + t] = val;
                            else if (g2 == 2) Rs[d2 * 7776 + t * 32 + hh] = val;
                            else              Xs[d2 * 7776 + t * 32 + hh] = val;
                        }
                    }
                }
        }
        __syncthreads();

        const float* vv = v + (size_t)(lay * 2) * 64;
        const float* bv = bbias + (size_t)(lay * 2) * 64;

        // serial c-chains: wave0 d0, wave1 d1; 8 steps per b128 group, c in-place in ZT
        if (w < 2 && lane < 32) {
            const int d = w, h = lane;
            const float vf = vv[d * 64 + h], bf_ = bv[d * 64 + h];
            const float kf = -LOG2E * vf;
            u16* Zr = &ZT[(d * 32 + h) * 248];
            u16* Fr = &FT[(d * 32 + h) * 248];
            bf16x8 z8 = *(const bf16x8*)&Zr[d ? 240 : 0];
            bf16x8 f8 = *(const bf16x8*)&Fr[d ? 240 : 0];
            float c = 0.f;
            for (int grp = 0; grp < 31; ++grp) {
                int gb  = d ? (30 - grp) * 8 : grp * 8;
                bf16x8 zn = z8, fn = f8;
                if (grp < 30) {
                    int gbn = d ? (29 - grp) * 8 : (grp + 1) * 8;
                    zn = *(const bf16x8*)&Zr[gbn];
                    fn = *(const bf16x8*)&Fr[gbn];
                }
                u16 co[8];
                #pragma unroll
                for (int k = 0; k < 8; ++k) {
                    int idx = d ? 7 - k : k;
                    int t = gb + idx;
                    float uz = (float)z8[idx];
                    float af = -LOG2E * ((float)f8[idx] + bf_);
                    if (t < TnN) {
                        float xe = fmaf(kf, c, af);
                        float fg = __builtin_amdgcn_rcpf(1.f + hw_exp2(xe));
                        c = fmaf(fg, c - uz, uz);
                        co[idx] = f2bf(c);
                    } else co[idx] = 0;
                }
                *(uint4*)&Zr[gb] = *(const uint4*)co;
                z8 = zn; f8 = fn;
            }
        }
        __syncthreads();

        // h-phase (parallel) + one-time guard zero
        if (lay == 0) {
            for (int i = tid; i < 21 * 72; i += 256) {
                int r = i / 72, ci = i - r * 72;
                int row = r < 7 ? r : (TnN + r);
                Hs[row * 72 + ci] = 0;
            }
        }
        for (int task = tid; task < 1984; task += 256) {
            int h = task & 31, d = (task >> 5) & 1, grp = task >> 6;
            int gb = grp * 8;
            const float vr_ = vv[d * 64 + 32 + h], br_ = bv[d * 64 + 32 + h];
            const float kr = -LOG2E * vr_;
            const u16* Cr = &ZT[(d * 32 + h) * 248];
            bf16x8 c8 = *(const bf16x8*)&Cr[gb];
            float cl[8];
            #pragma unroll
            for (int k = 0; k < 8; ++k) cl[k] = (float)c8[k];
            #pragma unroll
            for (int k = 0; k < 8; ++k) {
                int t = gb + k;
                if (t < TnN) {
                    float cpr;
                    if (d == 0) cpr = (t == 0) ? 0.f : (k ? cl[k - 1] : bf2f(Cr[gb - 1]));
                    else        cpr = (t == TnN - 1) ? 0.f : (k < 7 ? cl[k + 1] : bf2f(Cr[gb + 8]));
                    float ur = bf2f(Rs[d * 7776 + t * 32 + h]);
                    float ux = bf2f(Xs[d * 7776 + t * 32 + h]);
                    float xr = fmaf(kr, cpr, -LOG2E * (ur + br_));
                    float rg = __builtin_amdgcn_rcpf(1.f + hw_exp2(xr));
                    float hv = fmaf(rg, cl[k] - ux, ux);
                    Hs[(t + 7) * 72 + d * 32 + h] = f2bf(hv);
                }
            }
        }
        __syncthreads();
    }

    // ---- conv phase: A = Hs, scratch in dead ZT+ region ----
    {
        const int b = n >> 7, f = n & 127;
        u16* Bs = sh + ZT0;                       // 64 x 40
        float* Cf = (float*)(sh + ZT0 + 3072);    // 250 x 68 fp32
        f32x4 acc[4][4] = {};
        for (int kc = 0; kc < 16; ++kc) {
            int kk = kc >> 1, ci0 = (kc & 1) * 32;
            {
                int o = tid >> 2, grp = tid & 3;
                *(uint4*)&Bs[o * 40 + grp * 8] = *(const uint4*)&Wc[(size_t)o * 512 + kc * 32 + grp * 8];
            }
            __syncthreads();
            bf16x8 af[4], bfv[4];
            #pragma unroll
            for (int mt = 0; mt < 4; ++mt)
                af[mt] = *(const bf16x8*)&Hs[(w * 64 + mt * 16 + ml - kk + 7) * 72 + ci0 + q * 8];
            #pragma unroll
            for (int nt = 0; nt < 4; ++nt)
                bfv[nt] = *(const bf16x8*)&Bs[(nt * 16 + ml) * 40 + q * 8];
            #pragma unroll
            for (int mt = 0; mt < 4; ++mt)
                #pragma unroll
                for (int nt = 0; nt < 4; ++nt)
                    acc[mt][nt] = __builtin_amdgcn_mfma_f32_16x16x32_bf16(af[mt], bfv[nt], acc[mt][nt], 0, 0, 0);
            __syncthreads();
        }
        float bc[4];
        #pragma unroll
        for (int nt = 0; nt < 4; ++nt) bc[nt] = bct[nt * 16 + ml];
        #pragma unroll
        for (int mt = 0; mt < 4; ++mt)
            #pragma unroll
            for (int r = 0; r < 4; ++r) {
                int t = w * 64 + mt * 16 + q * 4 + r;
                if (t < Tt) {
                    #pragma unroll
                    for (int nt = 0; nt < 4; ++nt)
                        Cf[t * 68 + nt * 16 + ml] = acc[mt][nt][r] + bc[nt];
                }
            }
        __syncthreads();
        {
            const int sub = tid & 7;
            const int og = tid >> 3;
            #pragma unroll
            for (int half = 0; half < 2; ++half) {
                int o = og + half * 32;
                const float* xrow = x + ((size_t)(b * 64 + o) * 128 + f) * Tt;
                float* orow = out + ((size_t)(b * 64 + o) * 128 + f) * Tt;
                #pragma unroll
                for (int it = 0; it < 16; ++it) {
                    int j = it * 16 + sub * 2;
                    if (j < Tt) {
                        float2 xv = *(const float2*)&xrow[j];
                        float2 ov;
                        ov.x = Cf[j * 68 + o] + xv.x;
                        ov.y = Cf[(j + 1) * 68 + o] + xv.y;
                        *(float2*)&orow[j] = ov;
                    }
                }
            }
        }
    }
}

extern "C" void kernel_launch(void* const* d_in, const int* in_sizes, int n_in,
                              void* d_out, int out_size, void* d_ws, size_t ws_size,
                              hipStream_t stream) {
    (void)in_sizes; (void)n_in; (void)out_size; (void)ws_size;
    const float* x     = (const float*)d_in[0];
    const float* gamma = (const float*)d_in[1];
    const float* beta  = (const float*)d_in[2];
    const float* W0    = (const float*)d_in[3];
    const float* Wr    = (const float*)d_in[4];
    const float* v     = (const float*)d_in[5];
    const float* bb    = (const float*)d_in[6];
    const float* wct   = (const float*)d_in[7];
    const float* bct   = (const float*)d_in[8];
    float* out = (float*)d_out;

    char* base = (char*)d_ws;
    float* stats = (float*)base;
    u16* W0t  = (u16*)(base + 256);                      // 262144 B
    u16* Wrt  = (u16*)(base + 256 + 262144);             // 98304 B
    u16* Wcto = (u16*)(base + 256 + 262144 + 98304);     // 65536 B
    char* base2 = base + 426240;
    float* xu = (float*)base2;                           // 16.8 MB (dead after im2col)
    u16* U2   = (u16*)base2;                             // alias: 31.85 MB (live gemm0m->tail)
    char* base3 = base2 + 31850496;
    u16* Abig = (u16*)base3;                             // 63.7 MB (dead after gemm0m)

    hipMemsetAsync(stats, 0, 32, stream);
    k_stats<<<dim3(128, 2), 256, 0, stream>>>(x, stats);
    k_norm<<<(Nn * 64 * Tt + 255) / 256, 256, 0, stream>>>(x, stats, gamma, beta, xu);
    k_packw<<<(212992 + 255) / 256, 256, 0, stream>>>(W0, Wr, wct, W0t, Wrt, Wcto);
    k_im2col<<<dim3(8, 32), 256, 0, stream>>>(xu, Abig);

    k_gemm0m<<<dim3(486, 2), 256, 0, stream>>>(Abig, W0t, U2);
    k_tail<<<dim3(256), 256, 0, stream>>>(U2, Wrt, Wcto, v, bb, bct, x, out);
}

// Round 15
// 260.929 us; speedup vs baseline: 1.2513x; 1.2513x over previous
//
#include <hip/hip_runtime.h>
#include <math.h>

#define Tt 250
#define TnN 243
#define Nn 256
#define EPS_ 1e-5f
#define LOG2E 1.44269504f

typedef unsigned short u16;
typedef __bf16 bf16x8 __attribute__((ext_vector_type(8)));
typedef float f32x4 __attribute__((ext_vector_type(4)));

__device__ __forceinline__ u16 f2bf(float f) {
    unsigned u = __builtin_bit_cast(unsigned, f);
    u += 0x7FFFu + ((u >> 16) & 1u);
    return (u16)(u >> 16);
}
__device__ __forceinline__ float bf2f(u16 s) {
    unsigned u = ((unsigned)s) << 16;
    return __builtin_bit_cast(float, u);
}
__device__ __forceinline__ float hw_exp2(float x) {
    return __builtin_amdgcn_exp2f(x);
}

__device__ __forceinline__ void async_load16(const void* g, void* l) {
    __builtin_amdgcn_global_load_lds(
        (const __attribute__((address_space(1))) unsigned int*)g,
        (__attribute__((address_space(3))) unsigned int*)l, 16, 0, 0);
}

// DMA one 15,552 B plane (243x32 u16) global->LDS, 4 waves cooperate
__device__ __forceinline__ void dma_plane(const u16* gsrc, u16* ldst, int w, int lane) {
    const char* g = (const char*)gsrc;
    char* l = (char*)ldst;
    for (int off = w * 1024; off < 15552; off += 4096) {
        int rem = 15552 - off;
        int lim = rem < 1024 ? rem : 1024;
        if (lane * 16 < lim) async_load16(g + off + lane * 16, l + off);
    }
}

// serial c-chain over one transposed row pair, direction D compile-time:
// all vector extracts/inserts static -> registers only, no scratch.
template<int D>
__device__ __forceinline__ void chain_run(u16* Zr, u16* Fr, float kf, float bf_) {
    bf16x8 z8 = *(const bf16x8*)&Zr[D ? 240 : 0];
    bf16x8 f8 = *(const bf16x8*)&Fr[D ? 240 : 0];
    float c = 0.f;
    for (int grp = 0; grp < 31; ++grp) {
        int gb = D ? (30 - grp) * 8 : grp * 8;
        bf16x8 zn = z8, fn = f8;
        if (grp < 30) {
            int gbn = D ? (29 - grp) * 8 : (grp + 1) * 8;
            zn = *(const bf16x8*)&Zr[gbn];
            fn = *(const bf16x8*)&Fr[gbn];
        }
        bf16x8 co;
        #pragma unroll
        for (int k = 0; k < 8; ++k) {
            const int idx = D ? (7 - k) : k;     // constexpr after unroll
            int t = gb + idx;
            float uz = (float)z8[idx];
            float af = -LOG2E * ((float)f8[idx] + bf_);
            float xe = fmaf(kf, c, af);
            float fg = __builtin_amdgcn_rcpf(1.f + hw_exp2(xe));
            float cn = fmaf(fg, c - uz, uz);
            bool ok = (t < TnN);
            if (ok) c = cn;
            co[idx] = ok ? (__bf16)c : (__bf16)0.f;
        }
        *(bf16x8*)&Zr[gb] = co;
        z8 = zn; f8 = fn;
    }
}

// ---------------- stats ----------------
__global__ void k_stats(const float* __restrict__ x, float* __restrict__ stats) {
    int b = blockIdx.y;
    const float* xb = x + (size_t)b * 64 * 128 * Tt;
    const int n = 64 * 128 * Tt;
    float s = 0.f, s2 = 0.f;
    for (int i = blockIdx.x * blockDim.x + threadIdx.x; i < n; i += gridDim.x * blockDim.x) {
        float v = xb[i];
        s += v; s2 += v * v;
    }
    for (int off = 32; off; off >>= 1) {
        s  += __shfl_down(s, off);
        s2 += __shfl_down(s2, off);
    }
    __shared__ float ls[8], ls2[8];
    int lane = threadIdx.x & 63, w = threadIdx.x >> 6;
    if (lane == 0) { ls[w] = s; ls2[w] = s2; }
    __syncthreads();
    if (threadIdx.x == 0) {
        float a = 0.f, a2 = 0.f;
        int nw = blockDim.x >> 6;
        for (int i = 0; i < nw; i++) { a += ls[i]; a2 += ls2[i]; }
        atomicAdd(&stats[b * 2 + 0], a);
        atomicAdd(&stats[b * 2 + 1], a2);
    }
}

// ---------------- normalize ----------------
__global__ void k_norm(const float* __restrict__ x, const float* __restrict__ stats,
                       const float* __restrict__ gamma, const float* __restrict__ beta,
                       float* __restrict__ xu) {
    int idx = blockIdx.x * blockDim.x + threadIdx.x;
    const int total = Nn * 64 * Tt;
    if (idx >= total) return;
    int t = idx % Tt;
    int c = (idx / Tt) & 63;
    int n = idx / (Tt * 64);
    int b = n >> 7, f = n & 127;
    const float inv = 1.0f / (float)(64 * 128 * Tt);
    float mean = stats[b * 2 + 0] * inv;
    float var  = stats[b * 2 + 1] * inv - mean * mean;
    float rstd = rsqrtf(var + EPS_);
    float v = x[(((size_t)(b * 64 + c)) * 128 + f) * Tt + t];
    xu[((size_t)(n * 64 + c) << 8) + t] = (v - mean) * rstd * gamma[c] + beta[c];
}

// ---------------- pack weights ----------------
__global__ void k_packw(const float* __restrict__ W0, const float* __restrict__ Wr,
                        const float* __restrict__ wct,
                        u16* __restrict__ W0t, u16* __restrict__ Wrt, u16* __restrict__ Wcto) {
    int idx = blockIdx.x * blockDim.x + threadIdx.x;
    if (idx < 131072) {
        int j = idx >> 9, p = idx & 511;
        W0t[idx] = f2bf(W0[(size_t)(j >> 7) * 65536 + p * 128 + (j & 127)]);
    } else if (idx < 180224) {
        int r = idx - 131072;
        int i = r & 63, j = (r >> 6) & 255, lidx = r >> 14;
        Wrt[r] = f2bf(Wr[(size_t)(lidx * 2 + (j >> 7)) * 8192 + i * 128 + (j & 127)]);
    } else if (idx < 212992) {
        int r = idx - 180224;
        int o = r >> 9; int k = r & 511; int kk = k >> 6, ci = k & 63;
        Wcto[r] = f2bf(wct[(size_t)ci * 512 + o * 8 + kk]);
    }
}

// ---------------- im2col ----------------
__global__ __launch_bounds__(256) void k_im2col(const float* __restrict__ xu, u16* __restrict__ A) {
    __shared__ u16 lx[8][64][40];
    int t0 = blockIdx.x * 32;
    int n0 = blockIdx.y * 8;
    int tid = threadIdx.x;
    #pragma unroll
    for (int it = 0; it < 20; ++it) {
        int task = tid + it * 256;
        int v = task % 10;
        int c = (task / 10) & 63;
        int nn = task / 640;
        float4 f4 = *(const float4*)&xu[((size_t)((n0 + nn) * 64 + c) << 8) + t0 + v * 4];
        lx[nn][c][v * 4 + 0] = f2bf(f4.x);
        lx[nn][c][v * 4 + 1] = f2bf(f4.y);
        lx[nn][c][v * 4 + 2] = f2bf(f4.z);
        lx[nn][c][v * 4 + 3] = f2bf(f4.w);
    }
    __syncthreads();
    for (int it = 0; it < 64; ++it) {
        int task = it * 256 + tid;
        int c = task & 63, nn = (task >> 6) & 7, tt = task >> 9;
        int t = t0 + tt;
        if (t >= TnN) break;
        u16 tmp[8];
        #pragma unroll
        for (int j = 0; j < 8; ++j) tmp[j] = lx[nn][c][tt + j];
        uint4 o;
        o.x = (unsigned)tmp[0] | ((unsigned)tmp[1] << 16);
        o.y = (unsigned)tmp[2] | ((unsigned)tmp[3] << 16);
        o.z = (unsigned)tmp[4] | ((unsigned)tmp[5] << 16);
        o.w = (unsigned)tmp[6] | ((unsigned)tmp[7] << 16);
        *(uint4*)&A[((size_t)t * 256 + n0 + nn) * 512 + c * 8] = o;
    }
}

// ---------------- MFMA GEMM layer 0 -> U2 gate planes [n][d][g][243][32] ----------------
__global__ __launch_bounds__(256) void k_gemm0m(const u16* __restrict__ A,
                                                const u16* __restrict__ B,
                                                u16* __restrict__ U2) {
    __shared__ u16 sh[16384];
    u16* As = sh;
    u16* Bs = sh + 5120;
    const int tid = threadIdx.x;
    const size_t m0 = (size_t)blockIdx.x * 128;
    const int t = blockIdx.x >> 1;
    const int n0 = (blockIdx.x & 1) * 128;
    const int j0 = blockIdx.y * 128;
    const int d = blockIdx.y;
    const int lane = tid & 63, w = tid >> 6;
    const int wr = w >> 1, wc = w & 1;
    const int ml = lane & 15, q = lane >> 4;
    f32x4 acc[4][4] = {};
    for (int kc = 0; kc < 16; ++kc) {
        int c0 = kc * 32;
        #pragma unroll
        for (int i = 0; i < 2; ++i) {
            int task = tid + i * 256;
            int row = task >> 2, grp = task & 3;
            *(uint4*)&As[row * 40 + grp * 8] = *(const uint4*)&A[(m0 + row) * 512 + c0 + grp * 8];
            *(uint4*)&Bs[row * 40 + grp * 8] = *(const uint4*)&B[(size_t)(j0 + row) * 512 + c0 + grp * 8];
        }
        __syncthreads();
        bf16x8 af[4], bfv[4];
        #pragma unroll
        for (int mt = 0; mt < 4; ++mt) af[mt] = *(const bf16x8*)&As[(wr * 64 + mt * 16 + ml) * 40 + q * 8];
        #pragma unroll
        for (int nt = 0; nt < 4; ++nt) bfv[nt] = *(const bf16x8*)&Bs[(wc * 64 + nt * 16 + ml) * 40 + q * 8];
        #pragma unroll
        for (int mt = 0; mt < 4; ++mt)
            #pragma unroll
            for (int nt = 0; nt < 4; ++nt)
                acc[mt][nt] = __builtin_amdgcn_mfma_f32_16x16x32_bf16(af[mt], bfv[nt], acc[mt][nt], 0, 0, 0);
        __syncthreads();
    }
    u16* Cw = sh + w * 4096;
    #pragma unroll
    for (int mt = 0; mt < 4; ++mt)
        #pragma unroll
        for (int nt = 0; nt < 4; ++nt)
            #pragma unroll
            for (int r = 0; r < 4; ++r)
                Cw[(mt * 16 + q * 4 + r) * 64 + nt * 16 + ml] = f2bf(acc[mt][nt][r]);
    __syncthreads();
    #pragma unroll
    for (int it = 0; it < 8; ++it) {
        int task = it * 64 + lane;
        int grp = task & 7, row = task >> 3;
        int n = n0 + wr * 64 + row;
        int jj = wc * 64 + grp * 8;
        int g2 = jj >> 5;
        int h0 = jj & 31;
        *(uint4*)&U2[(((size_t)(n * 2 + d) * 4 + g2) * 7776) + t * 32 + h0] =
            *(const uint4*)&Cw[row * 64 + grp * 8];
    }
}

// ---------------- mega tail ----------------
// LDS map (u16 offsets): Hs 0..19007 (264x72), ZT 19008 (64x248), FT 34880 (64x248),
//                        Rs 50752 (2x243x32), Xs 66304 (2x243x32). Total 81856 u16 = 163,712 B
#define HS0 0
#define ZT0 19008
#define FT0 34880
#define RS0 50752
#define XS0 66304
#define SH_U16 81856
__global__ __launch_bounds__(256) void k_tail(const u16* __restrict__ U2,
                                              const u16* __restrict__ Wrt,
                                              const u16* __restrict__ Wc,
                                              const float* __restrict__ v,
                                              const float* __restrict__ bbias,
                                              const float* __restrict__ bct,
                                              const float* __restrict__ x,
                                              float* __restrict__ out) {
    __shared__ u16 sh[SH_U16];
    u16* Hs = sh + HS0;
    u16* ZT = sh + ZT0;
    u16* FT = sh + FT0;
    u16* Rs = sh + RS0;
    u16* Xs = sh + XS0;
    const int tid = threadIdx.x;
    const int n = blockIdx.x;
    const int lane = tid & 63, w = tid >> 6;
    const int ml = lane & 15, q = lane >> 4;
    const u16* U2n = U2 + (size_t)n * 62208;

    for (int lay = 0; lay < 4; ++lay) {
        if (lay == 0) {
            // round A: z planes -> Hs staging; r,x planes -> finals
            for (int d2 = 0; d2 < 2; ++d2) {
                dma_plane(U2n + (size_t)(d2 * 4 + 0) * 7776, Hs + d2 * 7776, w, lane);
                dma_plane(U2n + (size_t)(d2 * 4 + 2) * 7776, Rs + d2 * 7776, w, lane);
                dma_plane(U2n + (size_t)(d2 * 4 + 3) * 7776, Xs + d2 * 7776, w, lane);
            }
            __syncthreads();
            {   // transpose z: Hs[d][t][h] -> ZT[(d*32+h)][t]
                int cd = tid & 63, dd = cd >> 5, hh = cd & 31, tq = tid >> 6;
                int tb = tq * 61, te = tb + 61 < TnN ? tb + 61 : TnN;
                for (int t = tb; t < te; ++t)
                    ZT[cd * 248 + t] = Hs[dd * 7776 + t * 32 + hh];
            }
            __syncthreads();
            for (int d2 = 0; d2 < 2; ++d2)
                dma_plane(U2n + (size_t)(d2 * 4 + 1) * 7776, Hs + d2 * 7776, w, lane);
            __syncthreads();
            {   // transpose f
                int cd = tid & 63, dd = cd >> 5, hh = cd & 31, tq = tid >> 6;
                int tb = tq * 61, te = tb + 61 < TnN ? tb + 61 : TnN;
                for (int t = tb; t < te; ++t)
                    FT[cd * 248 + t] = Hs[dd * 7776 + t * 32 + hh];
            }
        } else {
            // B staging in (dead) ZT region
            u16* Bst = sh + ZT0;     // 256 x 72
            const u16* Wl = Wrt + (size_t)(lay - 1) * 16384;
            #pragma unroll
            for (int it = 0; it < 8; ++it) {
                int task = it * 256 + tid;
                int j = task >> 3, grp = task & 7;
                *(uint4*)&Bst[j * 72 + grp * 8] = *(const uint4*)&Wl[j * 64 + grp * 8];
            }
            __syncthreads();
            f32x4 acc[4][16];
            #pragma unroll
            for (int mt = 0; mt < 4; ++mt)
                #pragma unroll
                for (int nt = 0; nt < 16; ++nt)
                    acc[mt][nt] = (f32x4){0.f, 0.f, 0.f, 0.f};
            #pragma unroll
            for (int c2 = 0; c2 < 2; ++c2) {
                int c0 = c2 * 32;
                bf16x8 af[4];
                #pragma unroll
                for (int mt = 0; mt < 4; ++mt)
                    af[mt] = *(const bf16x8*)&Hs[(w * 64 + mt * 16 + ml + 7) * 72 + c0 + q * 8];
                #pragma unroll
                for (int nt = 0; nt < 16; ++nt) {
                    bf16x8 bfr = *(const bf16x8*)&Bst[(nt * 16 + ml) * 72 + c0 + q * 8];
                    #pragma unroll
                    for (int mt = 0; mt < 4; ++mt)
                        acc[mt][nt] = __builtin_amdgcn_mfma_f32_16x16x32_bf16(af[mt], bfr, acc[mt][nt], 0, 0, 0);
                }
            }
            __syncthreads();   // all B reads done -> ZT/FT writable
            #pragma unroll
            for (int mt = 0; mt < 4; ++mt)
                #pragma unroll
                for (int r = 0; r < 4; ++r) {
                    int t = w * 64 + mt * 16 + q * 4 + r;
                    if (t < TnN) {
                        #pragma unroll
                        for (int nt = 0; nt < 16; ++nt) {
                            int d2 = nt >> 3, g2 = (nt >> 1) & 3, hh = (nt & 1) * 16 + ml;
                            u16 val = f2bf(acc[mt][nt][r]);
                            if (g2 == 0)      ZT[(d2 * 32 + hh) * 248 + t] = val;
                            else if (g2 == 1) FT[(d2 * 32 + hh) * 248 + t] = val;
                            else if (g2 == 2) Rs[d2 * 7776 + t * 32 + hh] = val;
                            else              Xs[d2 * 7776 + t * 32 + hh] = val;
                        }
                    }
                }
        }
        __syncthreads();

        const float* vv = v + (size_t)(lay * 2) * 64;
        const float* bv = bbias + (size_t)(lay * 2) * 64;

        // serial c-chains: wave0 d0 (forward), wave1 d1 (backward); direction compile-time
        if (w < 2 && lane < 32) {
            const int d = w, h = lane;
            const float vf = vv[d * 64 + h], bf_ = bv[d * 64 + h];
            const float kf = -LOG2E * vf;
            u16* Zr = &ZT[(d * 32 + h) * 248];
            u16* Fr = &FT[(d * 32 + h) * 248];
            if (d == 0) chain_run<0>(Zr, Fr, kf, bf_);
            else        chain_run<1>(Zr, Fr, kf, bf_);
        }
        __syncthreads();

        // h-phase (parallel) + one-time guard zero
        if (lay == 0) {
            for (int i = tid; i < 21 * 72; i += 256) {
                int r = i / 72, ci = i - r * 72;
                int row = r < 7 ? r : (TnN + r);
                Hs[row * 72 + ci] = 0;
            }
        }
        for (int task = tid; task < 1984; task += 256) {
            int h = task & 31, d = (task >> 5) & 1, grp = task >> 6;
            int gb = grp * 8;
            const float vr_ = vv[d * 64 + 32 + h], br_ = bv[d * 64 + 32 + h];
            const float kr = -LOG2E * vr_;
            const u16* Cr = &ZT[(d * 32 + h) * 248];
            bf16x8 c8 = *(const bf16x8*)&Cr[gb];
            float cl[8];
            #pragma unroll
            for (int k = 0; k < 8; ++k) cl[k] = (float)c8[k];
            #pragma unroll
            for (int k = 0; k < 8; ++k) {
                int t = gb + k;
                if (t < TnN) {
                    float cpr;
                    if (d == 0) cpr = (t == 0) ? 0.f : (k ? cl[k - 1] : bf2f(Cr[gb - 1]));
                    else        cpr = (t == TnN - 1) ? 0.f : (k < 7 ? cl[k + 1] : bf2f(Cr[gb + 8]));
                    float ur = bf2f(Rs[d * 7776 + t * 32 + h]);
                    float ux = bf2f(Xs[d * 7776 + t * 32 + h]);
                    float xr = fmaf(kr, cpr, -LOG2E * (ur + br_));
                    float rg = __builtin_amdgcn_rcpf(1.f + hw_exp2(xr));
                    float hv = fmaf(rg, cl[k] - ux, ux);
                    Hs[(t + 7) * 72 + d * 32 + h] = f2bf(hv);
                }
            }
        }
        __syncthreads();
    }

    // ---- conv phase: A = Hs, scratch in dead ZT+ region ----
    {
        const int b = n >> 7, f = n & 127;
        u16* Bs = sh + ZT0;                       // 64 x 40
        float* Cf = (float*)(sh + ZT0 + 3072);    // 250 x 68 fp32
        f32x4 acc[4][4] = {};
        for (int kc = 0; kc < 16; ++kc) {
            int kk = kc >> 1, ci0 = (kc & 1) * 32;
            {
                int o = tid >> 2, grp = tid & 3;
                *(uint4*)&Bs[o * 40 + grp * 8] = *(const uint4*)&Wc[(size_t)o * 512 + kc * 32 + grp * 8];
            }
            __syncthreads();
            bf16x8 af[4], bfv[4];
            #pragma unroll
            for (int mt = 0; mt < 4; ++mt)
                af[mt] = *(const bf16x8*)&Hs[(w * 64 + mt * 16 + ml - kk + 7) * 72 + ci0 + q * 8];
            #pragma unroll
            for (int nt = 0; nt < 4; ++nt)
                bfv[nt] = *(const bf16x8*)&Bs[(nt * 16 + ml) * 40 + q * 8];
            #pragma unroll
            for (int mt = 0; mt < 4; ++mt)
                #pragma unroll
                for (int nt = 0; nt < 4; ++nt)
                    acc[mt][nt] = __builtin_amdgcn_mfma_f32_16x16x32_bf16(af[mt], bfv[nt], acc[mt][nt], 0, 0, 0);
            __syncthreads();
        }
        float bc[4];
        #pragma unroll
        for (int nt = 0; nt < 4; ++nt) bc[nt] = bct[nt * 16 + ml];
        #pragma unroll
        for (int mt = 0; mt < 4; ++mt)
            #pragma unroll
            for (int r = 0; r < 4; ++r) {
                int t = w * 64 + mt * 16 + q * 4 + r;
                if (t < Tt) {
                    #pragma unroll
                    for (int nt = 0; nt < 4; ++nt)
                        Cf[t * 68 + nt * 16 + ml] = acc[mt][nt][r] + bc[nt];
                }
            }
        __syncthreads();
        {
            const int sub = tid & 7;
            const int og = tid >> 3;
            #pragma unroll
            for (int half = 0; half < 2; ++half) {
                int o = og + half * 32;
                const float* xrow = x + ((size_t)(b * 64 + o) * 128 + f) * Tt;
                float* orow = out + ((size_t)(b * 64 + o) * 128 + f) * Tt;
                #pragma unroll
                for (int it = 0; it < 16; ++it) {
                    int j = it * 16 + sub * 2;
                    if (j < Tt) {
                        float2 xv = *(const float2*)&xrow[j];
                        float2 ov;
                        ov.x = Cf[j * 68 + o] + xv.x;
                        ov.y = Cf[(j + 1) * 68 + o] + xv.y;
                        *(float2*)&orow[j] = ov;
                    }
                }
            }
        }
    }
}

extern "C" void kernel_launch(void* const* d_in, const int* in_sizes, int n_in,
                              void* d_out, int out_size, void* d_ws, size_t ws_size,
                              hipStream_t stream) {
    (void)in_sizes; (void)n_in; (void)out_size; (void)ws_size;
    const float* x     = (const float*)d_in[0];
    const float* gamma = (const float*)d_in[1];
    const float* beta  = (const float*)d_in[2];
    const float* W0    = (const float*)d_in[3];
    const float* Wr    = (const float*)d_in[4];
    const float* v     = (const float*)d_in[5];
    const float* bb    = (const float*)d_in[6];
    const float* wct   = (const float*)d_in[7];
    const float* bct   = (const float*)d_in[8];
    float* out = (float*)d_out;

    char* base = (char*)d_ws;
    float* stats = (float*)base;
    u16* W0t  = (u16*)(base + 256);                      // 262144 B
    u16* Wrt  = (u16*)(base + 256 + 262144);             // 98304 B
    u16* Wcto = (u16*)(base + 256 + 262144 + 98304);     // 65536 B
    char* base2 = base + 426240;
    float* xu = (float*)base2;                           // 16.8 MB (dead after im2col)
    u16* U2   = (u16*)base2;                             // alias: 31.85 MB (live gemm0m->tail)
    char* base3 = base2 + 31850496;
    u16* Abig = (u16*)base3;                             // 63.7 MB (dead after gemm0m)

    hipMemsetAsync(stats, 0, 32, stream);
    k_stats<<<dim3(128, 2), 256, 0, stream>>>(x, stats);
    k_norm<<<(Nn * 64 * Tt + 255) / 256, 256, 0, stream>>>(x, stats, gamma, beta, xu);
    k_packw<<<(212992 + 255) / 256, 256, 0, stream>>>(W0, Wr, wct, W0t, Wrt, Wcto);
    k_im2col<<<dim3(8, 32), 256, 0, stream>>>(xu, Abig);

    k_gemm0m<<<dim3(486, 2), 256, 0, stream>>>(Abig, W0t, U2);
    k_tail<<<dim3(256), 256, 0, stream>>>(U2, Wrt, Wcto, v, bb, bct, x, out);
}